// Round 11
// baseline (275.021 us; speedup 1.0000x reference)
//
#include <hip/hip_runtime.h>
#include <math.h>

#define NTRI 12288

// ---- workspace layout (float offsets) ----
#define OFF_WT    0u            // 256*1280 ushort: combined (Wk@k_w/Wv@v_w) as B^T [c][k] bf16
#define OFF_PEKV  327680u       // 256*256   folded k/v bias + pe_img      [p][c]
#define OFF_CQWT  393216u       // (Wq@q_w) split bf16: cqwh[c][64] + cqwl[c][64]
#define OFF_PEQ   401408u       // 12288*128 Wq@(q_b+pe_tri)+bq            [n][c]
#define OFF_W2T   1974272u      // (conv_w@out_w) split bf16: w2h[oc][128] + w2l[oc][128]
#define OFF_B2    1982464u      // 64        conv_w@out_b + conv_b
#define OFF_INWT  1982528u      // 128*384   in_w transposed               [m][r]
#define OFF_KVPV  2031680u      // 4*5*256*256 ushort bf16 INTERLEAVED: [b][j][p][g*8: K4|V4]
#define OFF_GTAB  3342400u      // 4*5*12288*4  packed bilinear params (float4)

typedef short short8 __attribute__((ext_vector_type(8)));
typedef float f32x4 __attribute__((ext_vector_type(4)));

__device__ __forceinline__ unsigned short f2bf(float f) {
  unsigned u = __float_as_uint(f);
  return (unsigned short)((u + 0x7fff + ((u >> 16) & 1)) >> 16);
}
__device__ __forceinline__ float bflo(unsigned u) {
  return __uint_as_float(u << 16);
}
__device__ __forceinline__ float bfhi(unsigned u) {
  return __uint_as_float(u & 0xffff0000u);
}

// split-precision MFMA: acc += ah*bh + al*bh + ah*bl (al*bl ~2^-18, dropped)
__device__ __forceinline__ f32x4 mfma3(short8 ah, short8 al, short8 bh,
                                       short8 bl, f32x4 acc) {
  acc = __builtin_amdgcn_mfma_f32_16x16x32_bf16(ah, bh, acc, 0, 0, 0);
  acc = __builtin_amdgcn_mfma_f32_16x16x32_bf16(al, bh, acc, 0, 0, 0);
  acc = __builtin_amdgcn_mfma_f32_16x16x32_bf16(ah, bl, acc, 0, 0, 0);
  return acc;
}

// transpose in_w -> inwT[m][r]: lane-coalesced reads in k_pre's inner loops
__global__ __launch_bounds__(256) void k_inwT(const float* __restrict__ in_w,
                                              float* __restrict__ inwT) {
  int idx = blockIdx.x * 256 + threadIdx.x;  // 49152
  int r = idx >> 7, m = idx & 127;
  inwT[m * 384 + r] = in_w[idx];
}

// merged precompute: [0,1280) comb | [1280,1536) pekv | [1536,1568) cqw |
// [1568,3104) peq | [3104,3137) w2 | [3137,4097) grid
__global__ __launch_bounds__(256) void k_pre(const float* __restrict__ inwT,
    const float* __restrict__ k_w, const float* __restrict__ v_w,
    const float* __restrict__ k_b, const float* __restrict__ v_b,
    const float* __restrict__ in_b, const float* __restrict__ q_w,
    const float* __restrict__ q_b, const float* __restrict__ conv_w,
    const float* __restrict__ out_w, const float* __restrict__ out_b,
    const float* __restrict__ conv_b, const float* __restrict__ proj,
    unsigned short* __restrict__ wTc, float* __restrict__ pekv,
    unsigned short* __restrict__ cqwh, unsigned short* __restrict__ cqwl,
    float* __restrict__ peq,
    unsigned short* __restrict__ w2h, unsigned short* __restrict__ w2l,
    float* __restrict__ b2, float4* __restrict__ gtab) {
  __shared__ float spe8[8][128];
  __shared__ float skv[256];
  int bb = blockIdx.x;
  int t = threadIdx.x;

  if (bb < 1280) {
    // comb: wTc[c][i] = bf16( sum_m Wk/Wv[c][m] * (k_w|v_w)[m][i] )
    int i = bb, c = t;
    if (t < 128) skv[t] = k_w[(size_t)t * 1280 + i];
    else         skv[t] = v_w[(size_t)(t - 128) * 1280 + i];
    __syncthreads();
    const float* sp = (c < 128) ? skv : (skv + 128);
    float acc = 0.f;
    for (int m = 0; m < 128; ++m)
      acc += inwT[m * 384 + 128 + c] * sp[m];
    wTc[(size_t)c * 1280 + i] = f2bf(acc);
  } else if (bb < 1536) {
    // pekv
    int p = bb - 1280;
    if (t < 128) {
      float dv = __expf(-(float)(t & ~1) * (9.210340371976184f / 128.0f));
      float arg = (float)p * dv;
      spe8[0][t] = (t & 1) ? cosf(arg) : sinf(arg);
    }
    __syncthreads();
    const float* bias = (t < 128) ? k_b : v_b;
    float acc = 0.f;
    for (int m = 0; m < 128; ++m)
      acc += inwT[m * 384 + 128 + t] * (bias[m] + spe8[0][m]);
    pekv[p * 256 + t] = acc + in_b[128 + t];
  } else if (bb < 1568) {
    // cqw: split bf16, layout [c][k] (k-contiguous B-operand rows)
    int idx = (bb - 1536) * 256 + t;  // 8192
    int k = idx >> 7, c = idx & 127;
    float acc = 0.f;
    for (int m = 0; m < 128; ++m)
      acc += inwT[m * 384 + c] * q_w[m * 64 + k];
    unsigned short h = f2bf(acc);
    cqwh[c * 64 + k] = h;
    cqwl[c * 64 + k] = f2bf(acc - bflo(h));
  } else if (bb < 3104) {
    // peq
    int n8 = (bb - 1568) * 8;
    for (int it = 0; it < 4; ++it) {
      int e = it * 256 + t;  // < 1024
      int nn = e >> 7, m = e & 127;
      float dv = __expf(-(float)(m & ~1) * (9.210340371976184f / 128.0f));
      float arg = (float)(n8 + nn) * dv;
      spe8[nn][m] = q_b[m] + ((m & 1) ? cosf(arg) : sinf(arg));
    }
    __syncthreads();
    int c = t & 127, z = t >> 7;
    float a0 = 0, a1 = 0, a2 = 0, a3 = 0;
    for (int m = 0; m < 128; ++m) {
      float w = inwT[m * 384 + c];
      a0 += w * spe8[z * 4 + 0][m];
      a1 += w * spe8[z * 4 + 1][m];
      a2 += w * spe8[z * 4 + 2][m];
      a3 += w * spe8[z * 4 + 3][m];
    }
    float bbv = in_b[c];
    peq[(n8 + z * 4 + 0) * 128 + c] = a0 + bbv;
    peq[(n8 + z * 4 + 1) * 128 + c] = a1 + bbv;
    peq[(n8 + z * 4 + 2) * 128 + c] = a2 + bbv;
    peq[(n8 + z * 4 + 3) * 128 + c] = a3 + bbv;
  } else if (bb < 3137) {
    // w2: split bf16 [oc][c] (A-operand rows for phase-4 MFMA)
    int idx = (bb - 3104) * 256 + t;
    if (idx < 8192) {
      int c = idx >> 6, oc = idx & 63;
      float acc = 0.f;
      for (int m = 0; m < 128; ++m)
        acc += conv_w[oc * 128 + m] * out_w[m * 128 + c];
      unsigned short h = f2bf(acc);
      w2h[oc * 128 + c] = h;
      w2l[oc * 128 + c] = f2bf(acc - bflo(h));
    } else if (idx < 8256) {
      int oc = idx - 8192;
      float acc = 0.f;
      for (int m = 0; m < 128; ++m)
        acc += conv_w[oc * 128 + m] * out_b[m];
      b2[oc] = acc + conv_b[oc];
    }
  } else {
    // grid
    int idx = (bb - 3137) * 256 + t;  // 245760
    int n = idx % NTRI;
    int bj = idx / NTRI;
    int plane = n >> 12, rem = n & 4095;
    float fa = (float)(rem & 63), fb = (float)(rem >> 6);
    float cx, cy, cz;
    if (plane == 0)      { cx = fa;    cy = 31.5f; cz = fb; }
    else if (plane == 1) { cx = fa;    cy = fb;    cz = 31.5f; }
    else                 { cx = 31.5f; cy = fa;    cz = fb; }
    const float s2 = 2.20002f;
    cx = (cx / 63.0f - 0.5f) * s2;
    cy = (cy / 63.0f - 0.5f) * s2;
    cz = (cz / 63.0f - 0.5f) * s2;
    const float* P = &proj[bj * 16];
    float d0 = cx * P[0] + cy * P[1] + cz * P[2] + P[3];
    float d1 = cx * P[4] + cy * P[5] + cz * P[6] + P[7];
    float d2 = cx * P[8] + cy * P[9] + cz * P[10] + P[11];
    float x = d0 / d2 / 223.0f;
    float y = d1 / d2 / 223.0f;
    float gx = fminf(fmaxf((x - 0.5f) * 2.0f, -1.0f), 1.0f);
    float gy = fminf(fmaxf((y - 0.5f) * 2.0f, -1.0f), 1.0f);
    float ix = (gx + 1.0f) * 7.5f, iy = (gy + 1.0f) * 7.5f;
    float fx = floorf(ix), fy = floorf(iy);
    float wx = ix - fx, wy = iy - fy;
    int x0 = (int)fx; x0 = x0 < 0 ? 0 : (x0 > 15 ? 15 : x0);
    int y0 = (int)fy; y0 = y0 < 0 ? 0 : (y0 > 15 ? 15 : y0);
    int x1 = x0 + 1 > 15 ? 15 : x0 + 1;
    int y1 = y0 + 1 > 15 ? 15 : y0 + 1;
    int pack = x0 | (x1 << 8) | (y0 << 16) | (y1 << 24);
    gtab[idx] = make_float4(wx, wy, __int_as_float(pack), 0.f);
  }
}

// kvpv MFMA GEMM: C[5120][256] = imgrows(bf16) @ wTc^T + pekv, stored bf16.
// Output column remap: channel-group interleave so k_main loads K4+V4 as one
// uint4: old col c<128 (K ch c) -> (c>>2)*8 + (c&3); c>=128 (V) -> ...+4.
#define LDA 72
__global__ __launch_bounds__(256) void k_kv(const float* __restrict__ img,
    const unsigned short* __restrict__ wTc, const float* __restrict__ pekv,
    unsigned short* __restrict__ kv16) {
  __shared__ unsigned short sA[32 * LDA];
  __shared__ unsigned short sB[64 * LDA];
  int t = threadIdx.x;
  int gm = blockIdx.x >> 2;  // 0..159 (32-row tile)
  int gn = blockIdx.x & 3;   // 0..3
  int r0 = gm * 32, c0 = gn * 64;
  int lane = t & 63, w = t >> 6;
  int wm = w & 1, wn = w >> 1;
  int lrow = lane & 15, quad = lane >> 4;
  int srow = t >> 3, schunk = t & 7;   // staging: 16B chunk per thread
  int bj = gm >> 3;                    // uniform per block (32 | 256)
  f32x4 acc0 = {0,0,0,0}, acc1 = {0,0,0,0};

  float4 pA0, pA1;
  short8 pB0, pB1;
  auto issue = [&](int kt) {
    int k0 = kt * 64;
    const float4* s = (const float4*)&img[(size_t)(r0 + srow + bj + 1) * 1280 + k0 + schunk * 8];
    pA0 = s[0]; pA1 = s[1];
    pB0 = *(const short8*)&wTc[(size_t)(c0 + srow) * 1280 + k0 + schunk * 8];
    pB1 = *(const short8*)&wTc[(size_t)(c0 + srow + 32) * 1280 + k0 + schunk * 8];
  };
  issue(0);

  for (int kt = 0; kt < 20; ++kt) {
    __syncthreads();
    {
      short8 av;
      av[0] = (short)f2bf(pA0.x); av[1] = (short)f2bf(pA0.y);
      av[2] = (short)f2bf(pA0.z); av[3] = (short)f2bf(pA0.w);
      av[4] = (short)f2bf(pA1.x); av[5] = (short)f2bf(pA1.y);
      av[6] = (short)f2bf(pA1.z); av[7] = (short)f2bf(pA1.w);
      *(short8*)&sA[srow * LDA + schunk * 8] = av;
      *(short8*)&sB[srow * LDA + schunk * 8] = pB0;
      *(short8*)&sB[(srow + 32) * LDA + schunk * 8] = pB1;
    }
    __syncthreads();
    if (kt < 19) issue(kt + 1);  // in flight over the MFMA section
#pragma unroll
    for (int kk = 0; kk < 2; ++kk) {
      int kof = kk * 32 + quad * 8;
      short8 a  = *(const short8*)&sA[(wm * 16 + lrow) * LDA + kof];
      short8 b0 = *(const short8*)&sB[(wn * 32 + lrow) * LDA + kof];
      short8 b1 = *(const short8*)&sB[(wn * 32 + 16 + lrow) * LDA + kof];
      acc0 = __builtin_amdgcn_mfma_f32_16x16x32_bf16(a, b0, acc0, 0, 0, 0);
      acc1 = __builtin_amdgcn_mfma_f32_16x16x32_bf16(a, b1, acc1, 0, 0, 0);
    }
  }
  f32x4 accs[2] = {acc0, acc1};
#pragma unroll
  for (int ni = 0; ni < 2; ++ni)
#pragma unroll
    for (int r = 0; r < 4; ++r) {
      int grow = r0 + wm * 16 + quad * 4 + r;
      int gcol = c0 + wn * 32 + ni * 16 + lrow;
      int ncol = (gcol < 128) ? (((gcol >> 2) << 3) | (gcol & 3))
                              : ((((gcol - 128) >> 2) << 3) | 4 | (gcol & 3));
      kv16[(size_t)grow * 256 + ncol] =
          f2bf(accs[ni][r] + pekv[(grow & 255) * 256 + gcol]);
    }
}

// phase-3 j-body: consume G (gtab regs in place), issue next-s prefetch into
// G right after the Q addresses are computed (1 full s-iter of latency cover).
// All-static names (rule #20); arithmetic identical to rounds 7-10.
#define DO_J(J, G, VST, SC) {                                                  \
    int pack = __float_as_int(G.z);                                            \
    int x0 = pack & 255, x1 = (pack >> 8) & 255;                               \
    int y0 = (pack >> 16) & 255, y1 = (pack >> 24) & 255;                      \
    float wx = G.x, wy = G.y;                                                  \
    const unsigned short* r0 = Vb + J * 65536 + y0 * 4096;                     \
    const unsigned short* r1 = Vb + J * 65536 + y1 * 4096;                     \
    int i0 = x0 * 256 + sub * 8, i1 = x1 * 256 + sub * 8;                      \
    uint4 Q00 = *(const uint4*)(r0 + i0), Q01 = *(const uint4*)(r0 + i1);      \
    uint4 Q10 = *(const uint4*)(r1 + i0), Q11 = *(const uint4*)(r1 + i1);      \
    if (pf) G = gbase[(size_t)J * NTRI + nn];                                  \
    float w00 = (1.f - wx) * (1.f - wy), w01 = wx * (1.f - wy);                \
    float w10 = (1.f - wx) * wy, w11 = wx * wy;                                \
    float4 kc, vc;                                                             \
    kc.x = bflo(Q00.x) * w00 + bflo(Q01.x) * w01 + bflo(Q10.x) * w10 + bflo(Q11.x) * w11; \
    kc.y = bfhi(Q00.x) * w00 + bfhi(Q01.x) * w01 + bfhi(Q10.x) * w10 + bfhi(Q11.x) * w11; \
    kc.z = bflo(Q00.y) * w00 + bflo(Q01.y) * w01 + bflo(Q10.y) * w10 + bflo(Q11.y) * w11; \
    kc.w = bfhi(Q00.y) * w00 + bfhi(Q01.y) * w01 + bfhi(Q10.y) * w10 + bfhi(Q11.y) * w11; \
    vc.x = bflo(Q00.z) * w00 + bflo(Q01.z) * w01 + bflo(Q10.z) * w10 + bflo(Q11.z) * w11; \
    vc.y = bfhi(Q00.z) * w00 + bfhi(Q01.z) * w01 + bfhi(Q10.z) * w10 + bfhi(Q11.z) * w11; \
    vc.z = bflo(Q00.w) * w00 + bflo(Q01.w) * w01 + bflo(Q10.w) * w10 + bflo(Q11.w) * w11; \
    vc.w = bfhi(Q00.w) * w00 + bfhi(Q01.w) * w01 + bfhi(Q10.w) * w10 + bfhi(Q11.w) * w11; \
    VST = vc;                                                                  \
    float pa = qp4.x * kc.x + qp4.y * kc.y + qp4.z * kc.z + qp4.w * kc.w;      \
    pa += __shfl_xor(pa, 1);                                                   \
    pa += __shfl_xor(pa, 2);                                                   \
    SC = pa * 0.25f;                                                           \
  }

// fused: split-bf16 MFMA qp GEMM -> bf16 gather/lerp attention (batch
// softmax, interleaved uint4 K|V, in-place spread gtab prefetch, __expf)
// -> split-bf16 MFMA out-proj. LDS 25344 B, target 6 waves/SIMD.
__global__ __launch_bounds__(256, 6) void k_main(const float* __restrict__ tri,
    const unsigned short* __restrict__ cqwh, const unsigned short* __restrict__ cqwl,
    const float* __restrict__ peq,
    const unsigned short* __restrict__ w2h, const unsigned short* __restrict__ w2l,
    const float* __restrict__ b2,
    const unsigned short* __restrict__ kv16, const float4* __restrict__ gtab,
    float* __restrict__ outp) {
  __shared__ float smem[32 * 132 + 64 * 33];  // 25344 B
  float* sQP = smem;                  // [32][132] qp fp32 (phase 2..3)
  float* sO2 = smem;                  // overlay: O [pt][132] (written in 3)
  float* sTQ = smem + 32 * 132;       // [64][33] tq fp32 (phases 1-2)

  int t = threadIdx.x;
  int lane = t & 63, w = t >> 6;
  int b = blockIdx.x / 384;
  int n0 = (blockIdx.x % 384) * 32;

  // phase 1: stage tq fp32 -> LDS [k][pt] pitch 33
  for (int it = 0; it < 8; ++it) {
    int e = it * 256 + t;
    int k = e >> 5, pt = e & 31;
    sTQ[k * 33 + pt] = tri[(size_t)(b * 64 + k) * NTRI + n0 + pt];
  }
  __syncthreads();

  // phase 2: QP[pt][c] = tq @ cqw^T + peq via split-bf16 MFMA (validated r10)
  {
    int wm = w & 1, wn = w >> 1;
    int lrow = lane & 15, quad = lane >> 4;
    short8 ah0, al0, ah1, al1;
#pragma unroll
    for (int j = 0; j < 8; ++j) {
      float v0 = sTQ[(quad * 8 + j) * 33 + wm * 16 + lrow];
      float v1 = sTQ[(32 + quad * 8 + j) * 33 + wm * 16 + lrow];
      unsigned h0 = f2bf(v0);
      ah0[j] = (short)h0; al0[j] = (short)f2bf(v0 - bflo(h0));
      unsigned h1 = f2bf(v1);
      ah1[j] = (short)h1; al1[j] = (short)f2bf(v1 - bflo(h1));
    }
    const short8* Bh = (const short8*)&cqwh[(wn * 64 + lrow) * 64 + quad * 8];
    const short8* Bl = (const short8*)&cqwl[(wn * 64 + lrow) * 64 + quad * 8];
    f32x4 acc0 = {0,0,0,0}, acc1 = {0,0,0,0}, acc2 = {0,0,0,0}, acc3 = {0,0,0,0};
    acc0 = mfma3(ah0, al0, Bh[0],   Bl[0],   acc0);   // nt=0 ks=0
    acc0 = mfma3(ah1, al1, Bh[4],   Bl[4],   acc0);   // nt=0 ks=1
    acc1 = mfma3(ah0, al0, Bh[128], Bl[128], acc1);   // nt=1
    acc1 = mfma3(ah1, al1, Bh[132], Bl[132], acc1);
    acc2 = mfma3(ah0, al0, Bh[256], Bl[256], acc2);   // nt=2
    acc2 = mfma3(ah1, al1, Bh[260], Bl[260], acc2);
    acc3 = mfma3(ah0, al0, Bh[384], Bl[384], acc3);   // nt=3
    acc3 = mfma3(ah1, al1, Bh[388], Bl[388], acc3);
    int pt0 = wm * 16 + quad * 4;
    const float* pq = &peq[(size_t)(n0 + pt0) * 128 + wn * 64 + lrow];
#pragma unroll
    for (int r = 0; r < 4; ++r) {
      float* qrow = &sQP[(pt0 + r) * 132 + wn * 64 + lrow];
      qrow[0]  = acc0[r] + pq[r * 128 + 0];
      qrow[16] = acc1[r] + pq[r * 128 + 16];
      qrow[32] = acc2[r] + pq[r * 128 + 32];
      qrow[48] = acc3[r] + pq[r * 128 + 48];
    }
  }
  __syncthreads();

  // phase 3: attention. 32 lanes per point, 4 channels per lane.
  {
    int sub = lane & 31, half = lane >> 5, c4 = sub * 4;
    int pt0 = w * 2 + half;
    const unsigned short* Vb = kv16 + (size_t)b * 5 * 65536;
    const float4* gbase = &gtab[(size_t)(b * 5) * NTRI];
    float4 gA0, gA1, gA2, gA3, gA4;
    {
      int n = n0 + pt0;
      gA0 = gbase[(size_t)0 * NTRI + n];
      gA1 = gbase[(size_t)1 * NTRI + n];
      gA2 = gbase[(size_t)2 * NTRI + n];
      gA3 = gbase[(size_t)3 * NTRI + n];
      gA4 = gbase[(size_t)4 * NTRI + n];
    }
    for (int s = 0; s < 4; ++s) {
      int pt = s * 8 + pt0;
      float4 qp4 = *(const float4*)&sQP[pt * 132 + c4];
      bool pf = (s < 3);
      int nn = n0 + (s + 1) * 8 + pt0;
      float4 v0, v1, v2, v3, v4;
      float s0, s1, s2, s3, s4;
      DO_J(0, gA0, v0, s0)
      DO_J(1, gA1, v1, s1)
      DO_J(2, gA2, v2, s2)
      DO_J(3, gA3, v3, s3)
      DO_J(4, gA4, v4, s4)
      float mx = fmaxf(fmaxf(fmaxf(s0, s1), fmaxf(s2, s3)), s4);
      float e0 = __expf(s0 - mx), e1 = __expf(s1 - mx), e2 = __expf(s2 - mx);
      float e3 = __expf(s3 - mx), e4 = __expf(s4 - mx);
      float inv = 1.0f / (e0 + e1 + e2 + e3 + e4);
      float4 oa;
      oa.x = (e0 * v0.x + e1 * v1.x + e2 * v2.x + e3 * v3.x + e4 * v4.x) * inv;
      oa.y = (e0 * v0.y + e1 * v1.y + e2 * v2.y + e3 * v3.y + e4 * v4.y) * inv;
      oa.z = (e0 * v0.z + e1 * v1.z + e2 * v2.z + e3 * v3.z + e4 * v4.z) * inv;
      oa.w = (e0 * v0.w + e1 * v1.w + e2 * v2.w + e3 * v3.w + e4 * v4.w) * inv;
      *(float4*)&sO2[pt * 132 + c4] = oa;   // in-place, same pitch: race-free
    }
  }
  __syncthreads();

  // phase 4: FO[oc][pt] = W2 @ O + b2 via split-bf16 MFMA (validated r9).
  {
    int lrow = lane & 15, quad = lane >> 4;
    int oc0 = w * 16;
    const short8* Wh = (const short8*)&w2h[(oc0 + lrow) * 128 + quad * 8];
    const short8* Wl = (const short8*)&w2l[(oc0 + lrow) * 128 + quad * 8];
    f32x4 acc0 = {0,0,0,0}, acc1 = {0,0,0,0};
#pragma unroll
    for (int ks = 0; ks < 4; ++ks) {
      short8 wh = Wh[ks * 4], wl = Wl[ks * 4];
      const float* o0 = &sO2[lrow * 132 + ks * 32 + quad * 8];
      const float* o1 = &sO2[(16 + lrow) * 132 + ks * 32 + quad * 8];
      short8 bh0, bl0, bh1, bl1;
#pragma unroll
      for (int j = 0; j < 8; ++j) {
        float v0 = o0[j];
        unsigned h0 = f2bf(v0);
        bh0[j] = (short)h0; bl0[j] = (short)f2bf(v0 - bflo(h0));
        float v1 = o1[j];
        unsigned h1 = f2bf(v1);
        bh1[j] = (short)h1; bl1[j] = (short)f2bf(v1 - bflo(h1));
      }
      acc0 = mfma3(wh, wl, bh0, bl0, acc0);
      acc1 = mfma3(wh, wl, bh1, bl1, acc1);
    }
    float4 bb4 = *(const float4*)&b2[oc0 + quad * 4];
    size_t obase = (size_t)(b * 64 + oc0 + quad * 4) * NTRI + n0;
#pragma unroll
    for (int r = 0; r < 4; ++r) {
      float brv = (r == 0) ? bb4.x : (r == 1) ? bb4.y : (r == 2) ? bb4.z : bb4.w;
      outp[obase + (size_t)r * NTRI + lrow]      = acc0[r] + brv;
      outp[obase + (size_t)r * NTRI + 16 + lrow] = acc1[r] + brv;
    }
  }
}

extern "C" void kernel_launch(void* const* d_in, const int* in_sizes, int n_in,
                              void* d_out, int out_size, void* d_ws, size_t ws_size,
                              hipStream_t stream) {
  const float* tri    = (const float*)d_in[0];
  const float* img    = (const float*)d_in[1];
  const float* proj   = (const float*)d_in[2];
  const float* k_w    = (const float*)d_in[4];
  const float* k_b    = (const float*)d_in[5];
  const float* q_w    = (const float*)d_in[6];
  const float* q_b    = (const float*)d_in[7];
  const float* v_w    = (const float*)d_in[8];
  const float* v_b    = (const float*)d_in[9];
  const float* in_w   = (const float*)d_in[10];
  const float* in_b   = (const float*)d_in[11];
  const float* out_w  = (const float*)d_in[12];
  const float* out_b  = (const float*)d_in[13];
  const float* conv_w = (const float*)d_in[14];
  const float* conv_b = (const float*)d_in[15];
  float* ws = (float*)d_ws;
  unsigned short* wTc  = (unsigned short*)(ws + OFF_WT);
  float* pekv = ws + OFF_PEKV;
  unsigned short* cqwh = (unsigned short*)(ws + OFF_CQWT);
  unsigned short* cqwl = cqwh + 8192;
  float* peq  = ws + OFF_PEQ;
  unsigned short* w2h = (unsigned short*)(ws + OFF_W2T);
  unsigned short* w2l = w2h + 8192;
  float* b2   = ws + OFF_B2;
  float* inwT = ws + OFF_INWT;
  unsigned short* kv16 = (unsigned short*)(ws + OFF_KVPV);
  float* gtab = ws + OFF_GTAB;
  float* outp = (float*)d_out;

  k_inwT<<<192, 256, 0, stream>>>(in_w, inwT);
  k_pre<<<4097, 256, 0, stream>>>(inwT, k_w, v_w, k_b, v_b, in_b, q_w, q_b,
                                  conv_w, out_w, out_b, conv_b, proj,
                                  wTc, pekv, cqwh, cqwl, peq, w2h, w2l, b2,
                                  (float4*)gtab);
  k_kv<<<640, 256, 0, stream>>>(img, wTc, pekv, kv16);
  k_main<<<1536, 256, 0, stream>>>(tri, cqwh, cqwl, peq, w2h, w2l, b2, kv16,
                                   (const float4*)gtab, outp);
}

// Round 12
// 191.029 us; speedup vs baseline: 1.4397x; 1.4397x over previous
//
#include <hip/hip_runtime.h>
#include <math.h>

#define NTRI 12288

// ---- workspace layout (float offsets) ----
#define OFF_WT    0u            // 256*1280 ushort: combined (Wk@k_w/Wv@v_w) as B^T [c][k] bf16
#define OFF_PEKV  327680u       // 256*256   folded k/v bias + pe_img      [p][c]
#define OFF_CQWT  393216u       // (Wq@q_w) split bf16: cqwh[c][64] + cqwl[c][64]
#define OFF_PEQ   401408u       // 12288*128 Wq@(q_b+pe_tri)+bq            [n][c]
#define OFF_W2T   1974272u      // (conv_w@out_w) split bf16: w2h[oc][128] + w2l[oc][128]
#define OFF_B2    1982464u      // 64        conv_w@out_b + conv_b
#define OFF_INWT  1982528u      // 128*384   in_w transposed               [m][r]
#define OFF_KVPV  2031680u      // 4*5*256*256 ushort bf16 INTERLEAVED: [b][j][p][g*8: K4|V4]
#define OFF_GTAB  3342400u      // 4*5*12288*4  packed bilinear params (float4)

typedef short short8 __attribute__((ext_vector_type(8)));
typedef float f32x4 __attribute__((ext_vector_type(4)));

__device__ __forceinline__ unsigned short f2bf(float f) {
  unsigned u = __float_as_uint(f);
  return (unsigned short)((u + 0x7fff + ((u >> 16) & 1)) >> 16);
}
__device__ __forceinline__ float bflo(unsigned u) {
  return __uint_as_float(u << 16);
}
__device__ __forceinline__ float bfhi(unsigned u) {
  return __uint_as_float(u & 0xffff0000u);
}

// split-precision MFMA: acc += ah*bh + al*bh + ah*bl (al*bl ~2^-18, dropped)
__device__ __forceinline__ f32x4 mfma3(short8 ah, short8 al, short8 bh,
                                       short8 bl, f32x4 acc) {
  acc = __builtin_amdgcn_mfma_f32_16x16x32_bf16(ah, bh, acc, 0, 0, 0);
  acc = __builtin_amdgcn_mfma_f32_16x16x32_bf16(al, bh, acc, 0, 0, 0);
  acc = __builtin_amdgcn_mfma_f32_16x16x32_bf16(ah, bl, acc, 0, 0, 0);
  return acc;
}

// transpose in_w -> inwT[m][r]: lane-coalesced reads in k_pre's inner loops
__global__ __launch_bounds__(256) void k_inwT(const float* __restrict__ in_w,
                                              float* __restrict__ inwT) {
  int idx = blockIdx.x * 256 + threadIdx.x;  // 49152
  int r = idx >> 7, m = idx & 127;
  inwT[m * 384 + r] = in_w[idx];
}

// merged precompute: [0,1280) comb | [1280,1536) pekv | [1536,1568) cqw |
// [1568,3104) peq | [3104,3137) w2 | [3137,4097) grid
__global__ __launch_bounds__(256) void k_pre(const float* __restrict__ inwT,
    const float* __restrict__ k_w, const float* __restrict__ v_w,
    const float* __restrict__ k_b, const float* __restrict__ v_b,
    const float* __restrict__ in_b, const float* __restrict__ q_w,
    const float* __restrict__ q_b, const float* __restrict__ conv_w,
    const float* __restrict__ out_w, const float* __restrict__ out_b,
    const float* __restrict__ conv_b, const float* __restrict__ proj,
    unsigned short* __restrict__ wTc, float* __restrict__ pekv,
    unsigned short* __restrict__ cqwh, unsigned short* __restrict__ cqwl,
    float* __restrict__ peq,
    unsigned short* __restrict__ w2h, unsigned short* __restrict__ w2l,
    float* __restrict__ b2, float4* __restrict__ gtab) {
  __shared__ float spe8[8][128];
  __shared__ float skv[256];
  int bb = blockIdx.x;
  int t = threadIdx.x;

  if (bb < 1280) {
    // comb: wTc[c][i] = bf16( sum_m Wk/Wv[c][m] * (k_w|v_w)[m][i] )
    int i = bb, c = t;
    if (t < 128) skv[t] = k_w[(size_t)t * 1280 + i];
    else         skv[t] = v_w[(size_t)(t - 128) * 1280 + i];
    __syncthreads();
    const float* sp = (c < 128) ? skv : (skv + 128);
    float acc = 0.f;
    for (int m = 0; m < 128; ++m)
      acc += inwT[m * 384 + 128 + c] * sp[m];
    wTc[(size_t)c * 1280 + i] = f2bf(acc);
  } else if (bb < 1536) {
    // pekv
    int p = bb - 1280;
    if (t < 128) {
      float dv = __expf(-(float)(t & ~1) * (9.210340371976184f / 128.0f));
      float arg = (float)p * dv;
      spe8[0][t] = (t & 1) ? cosf(arg) : sinf(arg);
    }
    __syncthreads();
    const float* bias = (t < 128) ? k_b : v_b;
    float acc = 0.f;
    for (int m = 0; m < 128; ++m)
      acc += inwT[m * 384 + 128 + t] * (bias[m] + spe8[0][m]);
    pekv[p * 256 + t] = acc + in_b[128 + t];
  } else if (bb < 1568) {
    // cqw: split bf16, layout [c][k] (k-contiguous B-operand rows)
    int idx = (bb - 1536) * 256 + t;  // 8192
    int k = idx >> 7, c = idx & 127;
    float acc = 0.f;
    for (int m = 0; m < 128; ++m)
      acc += inwT[m * 384 + c] * q_w[m * 64 + k];
    unsigned short h = f2bf(acc);
    cqwh[c * 64 + k] = h;
    cqwl[c * 64 + k] = f2bf(acc - bflo(h));
  } else if (bb < 3104) {
    // peq
    int n8 = (bb - 1568) * 8;
    for (int it = 0; it < 4; ++it) {
      int e = it * 256 + t;  // < 1024
      int nn = e >> 7, m = e & 127;
      float dv = __expf(-(float)(m & ~1) * (9.210340371976184f / 128.0f));
      float arg = (float)(n8 + nn) * dv;
      spe8[nn][m] = q_b[m] + ((m & 1) ? cosf(arg) : sinf(arg));
    }
    __syncthreads();
    int c = t & 127, z = t >> 7;
    float a0 = 0, a1 = 0, a2 = 0, a3 = 0;
    for (int m = 0; m < 128; ++m) {
      float w = inwT[m * 384 + c];
      a0 += w * spe8[z * 4 + 0][m];
      a1 += w * spe8[z * 4 + 1][m];
      a2 += w * spe8[z * 4 + 2][m];
      a3 += w * spe8[z * 4 + 3][m];
    }
    float bbv = in_b[c];
    peq[(n8 + z * 4 + 0) * 128 + c] = a0 + bbv;
    peq[(n8 + z * 4 + 1) * 128 + c] = a1 + bbv;
    peq[(n8 + z * 4 + 2) * 128 + c] = a2 + bbv;
    peq[(n8 + z * 4 + 3) * 128 + c] = a3 + bbv;
  } else if (bb < 3137) {
    // w2: split bf16 [oc][c] (A-operand rows for phase-4 MFMA)
    int idx = (bb - 3104) * 256 + t;
    if (idx < 8192) {
      int c = idx >> 6, oc = idx & 63;
      float acc = 0.f;
      for (int m = 0; m < 128; ++m)
        acc += conv_w[oc * 128 + m] * out_w[m * 128 + c];
      unsigned short h = f2bf(acc);
      w2h[oc * 128 + c] = h;
      w2l[oc * 128 + c] = f2bf(acc - bflo(h));
    } else if (idx < 8256) {
      int oc = idx - 8192;
      float acc = 0.f;
      for (int m = 0; m < 128; ++m)
        acc += conv_w[oc * 128 + m] * out_b[m];
      b2[oc] = acc + conv_b[oc];
    }
  } else {
    // grid
    int idx = (bb - 3137) * 256 + t;  // 245760
    int n = idx % NTRI;
    int bj = idx / NTRI;
    int plane = n >> 12, rem = n & 4095;
    float fa = (float)(rem & 63), fb = (float)(rem >> 6);
    float cx, cy, cz;
    if (plane == 0)      { cx = fa;    cy = 31.5f; cz = fb; }
    else if (plane == 1) { cx = fa;    cy = fb;    cz = 31.5f; }
    else                 { cx = 31.5f; cy = fa;    cz = fb; }
    const float s2 = 2.20002f;
    cx = (cx / 63.0f - 0.5f) * s2;
    cy = (cy / 63.0f - 0.5f) * s2;
    cz = (cz / 63.0f - 0.5f) * s2;
    const float* P = &proj[bj * 16];
    float d0 = cx * P[0] + cy * P[1] + cz * P[2] + P[3];
    float d1 = cx * P[4] + cy * P[5] + cz * P[6] + P[7];
    float d2 = cx * P[8] + cy * P[9] + cz * P[10] + P[11];
    float x = d0 / d2 / 223.0f;
    float y = d1 / d2 / 223.0f;
    float gx = fminf(fmaxf((x - 0.5f) * 2.0f, -1.0f), 1.0f);
    float gy = fminf(fmaxf((y - 0.5f) * 2.0f, -1.0f), 1.0f);
    float ix = (gx + 1.0f) * 7.5f, iy = (gy + 1.0f) * 7.5f;
    float fx = floorf(ix), fy = floorf(iy);
    float wx = ix - fx, wy = iy - fy;
    int x0 = (int)fx; x0 = x0 < 0 ? 0 : (x0 > 15 ? 15 : x0);
    int y0 = (int)fy; y0 = y0 < 0 ? 0 : (y0 > 15 ? 15 : y0);
    int x1 = x0 + 1 > 15 ? 15 : x0 + 1;
    int y1 = y0 + 1 > 15 ? 15 : y0 + 1;
    int pack = x0 | (x1 << 8) | (y0 << 16) | (y1 << 24);
    gtab[idx] = make_float4(wx, wy, __int_as_float(pack), 0.f);
  }
}

// kvpv MFMA GEMM: C[5120][256] = imgrows(bf16) @ wTc^T + pekv, stored bf16.
// Output column remap: channel-group interleave so k_main loads K4+V4 as one
// uint4: old col c<128 (K ch c) -> (c>>2)*8 + (c&3); c>=128 (V) -> ...+4.
#define LDA 72
__global__ __launch_bounds__(256) void k_kv(const float* __restrict__ img,
    const unsigned short* __restrict__ wTc, const float* __restrict__ pekv,
    unsigned short* __restrict__ kv16) {
  __shared__ unsigned short sA[32 * LDA];
  __shared__ unsigned short sB[64 * LDA];
  int t = threadIdx.x;
  int gm = blockIdx.x >> 2;  // 0..159 (32-row tile)
  int gn = blockIdx.x & 3;   // 0..3
  int r0 = gm * 32, c0 = gn * 64;
  int lane = t & 63, w = t >> 6;
  int wm = w & 1, wn = w >> 1;
  int lrow = lane & 15, quad = lane >> 4;
  int srow = t >> 3, schunk = t & 7;   // staging: 16B chunk per thread
  int bj = gm >> 3;                    // uniform per block (32 | 256)
  f32x4 acc0 = {0,0,0,0}, acc1 = {0,0,0,0};

  float4 pA0, pA1;
  short8 pB0, pB1;
  auto issue = [&](int kt) {
    int k0 = kt * 64;
    const float4* s = (const float4*)&img[(size_t)(r0 + srow + bj + 1) * 1280 + k0 + schunk * 8];
    pA0 = s[0]; pA1 = s[1];
    pB0 = *(const short8*)&wTc[(size_t)(c0 + srow) * 1280 + k0 + schunk * 8];
    pB1 = *(const short8*)&wTc[(size_t)(c0 + srow + 32) * 1280 + k0 + schunk * 8];
  };
  issue(0);

  for (int kt = 0; kt < 20; ++kt) {
    __syncthreads();
    {
      short8 av;
      av[0] = (short)f2bf(pA0.x); av[1] = (short)f2bf(pA0.y);
      av[2] = (short)f2bf(pA0.z); av[3] = (short)f2bf(pA0.w);
      av[4] = (short)f2bf(pA1.x); av[5] = (short)f2bf(pA1.y);
      av[6] = (short)f2bf(pA1.z); av[7] = (short)f2bf(pA1.w);
      *(short8*)&sA[srow * LDA + schunk * 8] = av;
      *(short8*)&sB[srow * LDA + schunk * 8] = pB0;
      *(short8*)&sB[(srow + 32) * LDA + schunk * 8] = pB1;
    }
    __syncthreads();
    if (kt < 19) issue(kt + 1);  // in flight over the MFMA section
#pragma unroll
    for (int kk = 0; kk < 2; ++kk) {
      int kof = kk * 32 + quad * 8;
      short8 a  = *(const short8*)&sA[(wm * 16 + lrow) * LDA + kof];
      short8 b0 = *(const short8*)&sB[(wn * 32 + lrow) * LDA + kof];
      short8 b1 = *(const short8*)&sB[(wn * 32 + 16 + lrow) * LDA + kof];
      acc0 = __builtin_amdgcn_mfma_f32_16x16x32_bf16(a, b0, acc0, 0, 0, 0);
      acc1 = __builtin_amdgcn_mfma_f32_16x16x32_bf16(a, b1, acc1, 0, 0, 0);
    }
  }
  f32x4 accs[2] = {acc0, acc1};
#pragma unroll
  for (int ni = 0; ni < 2; ++ni)
#pragma unroll
    for (int r = 0; r < 4; ++r) {
      int grow = r0 + wm * 16 + quad * 4 + r;
      int gcol = c0 + wn * 32 + ni * 16 + lrow;
      int ncol = (gcol < 128) ? (((gcol >> 2) << 3) | (gcol & 3))
                              : ((((gcol - 128) >> 2) << 3) | 4 | (gcol & 3));
      kv16[(size_t)grow * 256 + ncol] =
          f2bf(accs[ni][r] + pekv[(grow & 255) * 256 + gcol]);
    }
}

// phase-3 j-body: consume G (gtab regs in place), issue next-s prefetch into
// G right after the Q addresses are computed (1 full s-iter of latency cover).
// All-static names (rule #20); arithmetic identical to rounds 7-10.
#define DO_J(J, G, VST, SC) {                                                  \
    int pack = __float_as_int(G.z);                                            \
    int x0 = pack & 255, x1 = (pack >> 8) & 255;                               \
    int y0 = (pack >> 16) & 255, y1 = (pack >> 24) & 255;                      \
    float wx = G.x, wy = G.y;                                                  \
    const unsigned short* r0 = Vb + J * 65536 + y0 * 4096;                     \
    const unsigned short* r1 = Vb + J * 65536 + y1 * 4096;                     \
    int i0 = x0 * 256 + sub * 8, i1 = x1 * 256 + sub * 8;                      \
    uint4 Q00 = *(const uint4*)(r0 + i0), Q01 = *(const uint4*)(r0 + i1);      \
    uint4 Q10 = *(const uint4*)(r1 + i0), Q11 = *(const uint4*)(r1 + i1);      \
    if (pf) G = gbase[(size_t)J * NTRI + nn];                                  \
    float w00 = (1.f - wx) * (1.f - wy), w01 = wx * (1.f - wy);                \
    float w10 = (1.f - wx) * wy, w11 = wx * wy;                                \
    float4 kc, vc;                                                             \
    kc.x = bflo(Q00.x) * w00 + bflo(Q01.x) * w01 + bflo(Q10.x) * w10 + bflo(Q11.x) * w11; \
    kc.y = bfhi(Q00.x) * w00 + bfhi(Q01.x) * w01 + bfhi(Q10.x) * w10 + bfhi(Q11.x) * w11; \
    kc.z = bflo(Q00.y) * w00 + bflo(Q01.y) * w01 + bflo(Q10.y) * w10 + bflo(Q11.y) * w11; \
    kc.w = bfhi(Q00.y) * w00 + bfhi(Q01.y) * w01 + bfhi(Q10.y) * w10 + bfhi(Q11.y) * w11; \
    vc.x = bflo(Q00.z) * w00 + bflo(Q01.z) * w01 + bflo(Q10.z) * w10 + bflo(Q11.z) * w11; \
    vc.y = bfhi(Q00.z) * w00 + bfhi(Q01.z) * w01 + bfhi(Q10.z) * w10 + bfhi(Q11.z) * w11; \
    vc.z = bflo(Q00.w) * w00 + bflo(Q01.w) * w01 + bflo(Q10.w) * w10 + bflo(Q11.w) * w11; \
    vc.w = bfhi(Q00.w) * w00 + bfhi(Q01.w) * w01 + bfhi(Q10.w) * w10 + bfhi(Q11.w) * w11; \
    VST = vc;                                                                  \
    float pa = qp4.x * kc.x + qp4.y * kc.y + qp4.z * kc.z + qp4.w * kc.w;      \
    pa += __shfl_xor(pa, 1);                                                   \
    pa += __shfl_xor(pa, 2);                                                   \
    SC = pa * 0.25f;                                                           \
  }

// fused: split-bf16 MFMA qp GEMM -> bf16 gather/lerp attention (batch
// softmax, interleaved uint4 K|V, in-place spread gtab prefetch, __expf)
// -> split-bf16 MFMA out-proj. LDS 25344 B. (256,2): round-11's (256,6)
// cap forced VGPR 92->40 and 300MB of spill traffic — occupancy is NOT a
// usable lever here; the register floor of the batched gather is ~90.
__global__ __launch_bounds__(256, 2) void k_main(const float* __restrict__ tri,
    const unsigned short* __restrict__ cqwh, const unsigned short* __restrict__ cqwl,
    const float* __restrict__ peq,
    const unsigned short* __restrict__ w2h, const unsigned short* __restrict__ w2l,
    const float* __restrict__ b2,
    const unsigned short* __restrict__ kv16, const float4* __restrict__ gtab,
    float* __restrict__ outp) {
  __shared__ float smem[32 * 132 + 64 * 33];  // 25344 B
  float* sQP = smem;                  // [32][132] qp fp32 (phase 2..3)
  float* sO2 = smem;                  // overlay: O [pt][132] (written in 3)
  float* sTQ = smem + 32 * 132;       // [64][33] tq fp32 (phases 1-2)

  int t = threadIdx.x;
  int lane = t & 63, w = t >> 6;
  int b = blockIdx.x / 384;
  int n0 = (blockIdx.x % 384) * 32;

  // phase 1: stage tq fp32 -> LDS [k][pt] pitch 33
  for (int it = 0; it < 8; ++it) {
    int e = it * 256 + t;
    int k = e >> 5, pt = e & 31;
    sTQ[k * 33 + pt] = tri[(size_t)(b * 64 + k) * NTRI + n0 + pt];
  }
  __syncthreads();

  // phase 2: QP[pt][c] = tq @ cqw^T + peq via split-bf16 MFMA (validated r10)
  {
    int wm = w & 1, wn = w >> 1;
    int lrow = lane & 15, quad = lane >> 4;
    short8 ah0, al0, ah1, al1;
#pragma unroll
    for (int j = 0; j < 8; ++j) {
      float v0 = sTQ[(quad * 8 + j) * 33 + wm * 16 + lrow];
      float v1 = sTQ[(32 + quad * 8 + j) * 33 + wm * 16 + lrow];
      unsigned h0 = f2bf(v0);
      ah0[j] = (short)h0; al0[j] = (short)f2bf(v0 - bflo(h0));
      unsigned h1 = f2bf(v1);
      ah1[j] = (short)h1; al1[j] = (short)f2bf(v1 - bflo(h1));
    }
    const short8* Bh = (const short8*)&cqwh[(wn * 64 + lrow) * 64 + quad * 8];
    const short8* Bl = (const short8*)&cqwl[(wn * 64 + lrow) * 64 + quad * 8];
    f32x4 acc0 = {0,0,0,0}, acc1 = {0,0,0,0}, acc2 = {0,0,0,0}, acc3 = {0,0,0,0};
    acc0 = mfma3(ah0, al0, Bh[0],   Bl[0],   acc0);   // nt=0 ks=0
    acc0 = mfma3(ah1, al1, Bh[4],   Bl[4],   acc0);   // nt=0 ks=1
    acc1 = mfma3(ah0, al0, Bh[128], Bl[128], acc1);   // nt=1
    acc1 = mfma3(ah1, al1, Bh[132], Bl[132], acc1);
    acc2 = mfma3(ah0, al0, Bh[256], Bl[256], acc2);   // nt=2
    acc2 = mfma3(ah1, al1, Bh[260], Bl[260], acc2);
    acc3 = mfma3(ah0, al0, Bh[384], Bl[384], acc3);   // nt=3
    acc3 = mfma3(ah1, al1, Bh[388], Bl[388], acc3);
    int pt0 = wm * 16 + quad * 4;
    const float* pq = &peq[(size_t)(n0 + pt0) * 128 + wn * 64 + lrow];
#pragma unroll
    for (int r = 0; r < 4; ++r) {
      float* qrow = &sQP[(pt0 + r) * 132 + wn * 64 + lrow];
      qrow[0]  = acc0[r] + pq[r * 128 + 0];
      qrow[16] = acc1[r] + pq[r * 128 + 16];
      qrow[32] = acc2[r] + pq[r * 128 + 32];
      qrow[48] = acc3[r] + pq[r * 128 + 48];
    }
  }
  __syncthreads();

  // phase 3: attention. 32 lanes per point, 4 channels per lane.
  {
    int sub = lane & 31, half = lane >> 5, c4 = sub * 4;
    int pt0 = w * 2 + half;
    const unsigned short* Vb = kv16 + (size_t)b * 5 * 65536;
    const float4* gbase = &gtab[(size_t)(b * 5) * NTRI];
    float4 gA0, gA1, gA2, gA3, gA4;
    {
      int n = n0 + pt0;
      gA0 = gbase[(size_t)0 * NTRI + n];
      gA1 = gbase[(size_t)1 * NTRI + n];
      gA2 = gbase[(size_t)2 * NTRI + n];
      gA3 = gbase[(size_t)3 * NTRI + n];
      gA4 = gbase[(size_t)4 * NTRI + n];
    }
    for (int s = 0; s < 4; ++s) {
      int pt = s * 8 + pt0;
      float4 qp4 = *(const float4*)&sQP[pt * 132 + c4];
      bool pf = (s < 3);
      int nn = n0 + (s + 1) * 8 + pt0;
      float4 v0, v1, v2, v3, v4;
      float s0, s1, s2, s3, s4;
      DO_J(0, gA0, v0, s0)
      DO_J(1, gA1, v1, s1)
      DO_J(2, gA2, v2, s2)
      DO_J(3, gA3, v3, s3)
      DO_J(4, gA4, v4, s4)
      float mx = fmaxf(fmaxf(fmaxf(s0, s1), fmaxf(s2, s3)), s4);
      float e0 = __expf(s0 - mx), e1 = __expf(s1 - mx), e2 = __expf(s2 - mx);
      float e3 = __expf(s3 - mx), e4 = __expf(s4 - mx);
      float inv = 1.0f / (e0 + e1 + e2 + e3 + e4);
      float4 oa;
      oa.x = (e0 * v0.x + e1 * v1.x + e2 * v2.x + e3 * v3.x + e4 * v4.x) * inv;
      oa.y = (e0 * v0.y + e1 * v1.y + e2 * v2.y + e3 * v3.y + e4 * v4.y) * inv;
      oa.z = (e0 * v0.z + e1 * v1.z + e2 * v2.z + e3 * v3.z + e4 * v4.z) * inv;
      oa.w = (e0 * v0.w + e1 * v1.w + e2 * v2.w + e3 * v3.w + e4 * v4.w) * inv;
      *(float4*)&sO2[pt * 132 + c4] = oa;   // in-place, same pitch: race-free
    }
  }
  __syncthreads();

  // phase 4: FO[oc][pt] = W2 @ O + b2 via split-bf16 MFMA (validated r9).
  {
    int lrow = lane & 15, quad = lane >> 4;
    int oc0 = w * 16;
    const short8* Wh = (const short8*)&w2h[(oc0 + lrow) * 128 + quad * 8];
    const short8* Wl = (const short8*)&w2l[(oc0 + lrow) * 128 + quad * 8];
    f32x4 acc0 = {0,0,0,0}, acc1 = {0,0,0,0};
#pragma unroll
    for (int ks = 0; ks < 4; ++ks) {
      short8 wh = Wh[ks * 4], wl = Wl[ks * 4];
      const float* o0 = &sO2[lrow * 132 + ks * 32 + quad * 8];
      const float* o1 = &sO2[(16 + lrow) * 132 + ks * 32 + quad * 8];
      short8 bh0, bl0, bh1, bl1;
#pragma unroll
      for (int j = 0; j < 8; ++j) {
        float v0 = o0[j];
        unsigned h0 = f2bf(v0);
        bh0[j] = (short)h0; bl0[j] = (short)f2bf(v0 - bflo(h0));
        float v1 = o1[j];
        unsigned h1 = f2bf(v1);
        bh1[j] = (short)h1; bl1[j] = (short)f2bf(v1 - bflo(h1));
      }
      acc0 = mfma3(wh, wl, bh0, bl0, acc0);
      acc1 = mfma3(wh, wl, bh1, bl1, acc1);
    }
    float4 bb4 = *(const float4*)&b2[oc0 + quad * 4];
    size_t obase = (size_t)(b * 64 + oc0 + quad * 4) * NTRI + n0;
#pragma unroll
    for (int r = 0; r < 4; ++r) {
      float brv = (r == 0) ? bb4.x : (r == 1) ? bb4.y : (r == 2) ? bb4.z : bb4.w;
      outp[obase + (size_t)r * NTRI + lrow]      = acc0[r] + brv;
      outp[obase + (size_t)r * NTRI + 16 + lrow] = acc1[r] + brv;
    }
  }
}

extern "C" void kernel_launch(void* const* d_in, const int* in_sizes, int n_in,
                              void* d_out, int out_size, void* d_ws, size_t ws_size,
                              hipStream_t stream) {
  const float* tri    = (const float*)d_in[0];
  const float* img    = (const float*)d_in[1];
  const float* proj   = (const float*)d_in[2];
  const float* k_w    = (const float*)d_in[4];
  const float* k_b    = (const float*)d_in[5];
  const float* q_w    = (const float*)d_in[6];
  const float* q_b    = (const float*)d_in[7];
  const float* v_w    = (const float*)d_in[8];
  const float* v_b    = (const float*)d_in[9];
  const float* in_w   = (const float*)d_in[10];
  const float* in_b   = (const float*)d_in[11];
  const float* out_w  = (const float*)d_in[12];
  const float* out_b  = (const float*)d_in[13];
  const float* conv_w = (const float*)d_in[14];
  const float* conv_b = (const float*)d_in[15];
  float* ws = (float*)d_ws;
  unsigned short* wTc  = (unsigned short*)(ws + OFF_WT);
  float* pekv = ws + OFF_PEKV;
  unsigned short* cqwh = (unsigned short*)(ws + OFF_CQWT);
  unsigned short* cqwl = cqwh + 8192;
  float* peq  = ws + OFF_PEQ;
  unsigned short* w2h = (unsigned short*)(ws + OFF_W2T);
  unsigned short* w2l = w2h + 8192;
  float* b2   = ws + OFF_B2;
  float* inwT = ws + OFF_INWT;
  unsigned short* kv16 = (unsigned short*)(ws + OFF_KVPV);
  float* gtab = ws + OFF_GTAB;
  float* outp = (float*)d_out;

  k_inwT<<<192, 256, 0, stream>>>(in_w, inwT);
  k_pre<<<4097, 256, 0, stream>>>(inwT, k_w, v_w, k_b, v_b, in_b, q_w, q_b,
                                  conv_w, out_w, out_b, conv_b, proj,
                                  wTc, pekv, cqwh, cqwl, peq, w2h, w2l, b2,
                                  (float4*)gtab);
  k_kv<<<640, 256, 0, stream>>>(img, wTc, pekv, kv16);
  k_main<<<1536, 256, 0, stream>>>(tri, cqwh, cqwl, peq, w2h, w2l, b2, kv16,
                                   (const float4*)gtab, outp);
}

// Round 14
// 185.114 us; speedup vs baseline: 1.4857x; 1.0320x over previous
//
#include <hip/hip_runtime.h>
#include <math.h>

#define NTRI 12288

// ---- workspace layout (float offsets) ----
#define OFF_WT    0u            // 256*1280 ushort: combined (Wk@k_w/Wv@v_w) as B^T [c][k] bf16
#define OFF_PEKV  327680u       // 256*256   folded k/v bias + pe_img      [p][c]
#define OFF_CQWT  393216u       // (Wq@q_w) split bf16: cqwh[c][64] + cqwl[c][64]
#define OFF_PEQ   401408u       // 12288*128 Wq@(q_b+pe_tri)+bq            [n][c]
#define OFF_W2T   1974272u      // (conv_w@out_w) split bf16: w2h[oc][128] + w2l[oc][128]
#define OFF_B2    1982464u      // 64        conv_w@out_b + conv_b
#define OFF_INWT  1982528u      // 128*384   in_w transposed               [m][r]
#define OFF_KVPV  2031680u      // 4*5*256*256 ushort bf16 INTERLEAVED: [b][j][p][g*8: K4|V4]
#define OFF_GTAB  3342400u      // 4*5*12288*4  packed bilinear params (float4)

typedef short short8 __attribute__((ext_vector_type(8)));
typedef float f32x4 __attribute__((ext_vector_type(4)));

__device__ __forceinline__ unsigned short f2bf(float f) {
  unsigned u = __float_as_uint(f);
  return (unsigned short)((u + 0x7fff + ((u >> 16) & 1)) >> 16);
}
__device__ __forceinline__ float bflo(unsigned u) {
  return __uint_as_float(u << 16);
}
__device__ __forceinline__ float bfhi(unsigned u) {
  return __uint_as_float(u & 0xffff0000u);
}

// split-precision MFMA: acc += ah*bh + al*bh + ah*bl (al*bl ~2^-18, dropped)
__device__ __forceinline__ f32x4 mfma3(short8 ah, short8 al, short8 bh,
                                       short8 bl, f32x4 acc) {
  acc = __builtin_amdgcn_mfma_f32_16x16x32_bf16(ah, bh, acc, 0, 0, 0);
  acc = __builtin_amdgcn_mfma_f32_16x16x32_bf16(al, bh, acc, 0, 0, 0);
  acc = __builtin_amdgcn_mfma_f32_16x16x32_bf16(ah, bl, acc, 0, 0, 0);
  return acc;
}

// transpose in_w -> inwT[m][r]: lane-coalesced reads in k_pre's inner loops
__global__ __launch_bounds__(256) void k_inwT(const float* __restrict__ in_w,
                                              float* __restrict__ inwT) {
  int idx = blockIdx.x * 256 + threadIdx.x;  // 49152
  int r = idx >> 7, m = idx & 127;
  inwT[m * 384 + r] = in_w[idx];
}

// merged precompute: [0,1280) comb | [1280,1536) pekv | [1536,1568) cqw |
// [1568,3104) peq | [3104,3137) w2 | [3137,4097) grid
__global__ __launch_bounds__(256) void k_pre(const float* __restrict__ inwT,
    const float* __restrict__ k_w, const float* __restrict__ v_w,
    const float* __restrict__ k_b, const float* __restrict__ v_b,
    const float* __restrict__ in_b, const float* __restrict__ q_w,
    const float* __restrict__ q_b, const float* __restrict__ conv_w,
    const float* __restrict__ out_w, const float* __restrict__ out_b,
    const float* __restrict__ conv_b, const float* __restrict__ proj,
    unsigned short* __restrict__ wTc, float* __restrict__ pekv,
    unsigned short* __restrict__ cqwh, unsigned short* __restrict__ cqwl,
    float* __restrict__ peq,
    unsigned short* __restrict__ w2h, unsigned short* __restrict__ w2l,
    float* __restrict__ b2, float4* __restrict__ gtab) {
  __shared__ float spe8[8][128];
  __shared__ float skv[256];
  int bb = blockIdx.x;
  int t = threadIdx.x;

  if (bb < 1280) {
    // comb: wTc[c][i] = bf16( sum_m Wk/Wv[c][m] * (k_w|v_w)[m][i] )
    int i = bb, c = t;
    if (t < 128) skv[t] = k_w[(size_t)t * 1280 + i];
    else         skv[t] = v_w[(size_t)(t - 128) * 1280 + i];
    __syncthreads();
    const float* sp = (c < 128) ? skv : (skv + 128);
    float acc = 0.f;
    for (int m = 0; m < 128; ++m)
      acc += inwT[m * 384 + 128 + c] * sp[m];
    wTc[(size_t)c * 1280 + i] = f2bf(acc);
  } else if (bb < 1536) {
    // pekv
    int p = bb - 1280;
    if (t < 128) {
      float dv = __expf(-(float)(t & ~1) * (9.210340371976184f / 128.0f));
      float arg = (float)p * dv;
      spe8[0][t] = (t & 1) ? cosf(arg) : sinf(arg);
    }
    __syncthreads();
    const float* bias = (t < 128) ? k_b : v_b;
    float acc = 0.f;
    for (int m = 0; m < 128; ++m)
      acc += inwT[m * 384 + 128 + t] * (bias[m] + spe8[0][m]);
    pekv[p * 256 + t] = acc + in_b[128 + t];
  } else if (bb < 1568) {
    // cqw: split bf16, layout [c][k] (k-contiguous B-operand rows)
    int idx = (bb - 1536) * 256 + t;  // 8192
    int k = idx >> 7, c = idx & 127;
    float acc = 0.f;
    for (int m = 0; m < 128; ++m)
      acc += inwT[m * 384 + c] * q_w[m * 64 + k];
    unsigned short h = f2bf(acc);
    cqwh[c * 64 + k] = h;
    cqwl[c * 64 + k] = f2bf(acc - bflo(h));
  } else if (bb < 3104) {
    // peq
    int n8 = (bb - 1568) * 8;
    for (int it = 0; it < 4; ++it) {
      int e = it * 256 + t;  // < 1024
      int nn = e >> 7, m = e & 127;
      float dv = __expf(-(float)(m & ~1) * (9.210340371976184f / 128.0f));
      float arg = (float)(n8 + nn) * dv;
      spe8[nn][m] = q_b[m] + ((m & 1) ? cosf(arg) : sinf(arg));
    }
    __syncthreads();
    int c = t & 127, z = t >> 7;
    float a0 = 0, a1 = 0, a2 = 0, a3 = 0;
    for (int m = 0; m < 128; ++m) {
      float w = inwT[m * 384 + c];
      a0 += w * spe8[z * 4 + 0][m];
      a1 += w * spe8[z * 4 + 1][m];
      a2 += w * spe8[z * 4 + 2][m];
      a3 += w * spe8[z * 4 + 3][m];
    }
    float bbv = in_b[c];
    peq[(n8 + z * 4 + 0) * 128 + c] = a0 + bbv;
    peq[(n8 + z * 4 + 1) * 128 + c] = a1 + bbv;
    peq[(n8 + z * 4 + 2) * 128 + c] = a2 + bbv;
    peq[(n8 + z * 4 + 3) * 128 + c] = a3 + bbv;
  } else if (bb < 3137) {
    // w2: split bf16 [oc][c] (A-operand rows for phase-4 MFMA)
    int idx = (bb - 3104) * 256 + t;
    if (idx < 8192) {
      int c = idx >> 6, oc = idx & 63;
      float acc = 0.f;
      for (int m = 0; m < 128; ++m)
        acc += conv_w[oc * 128 + m] * out_w[m * 128 + c];
      unsigned short h = f2bf(acc);
      w2h[oc * 128 + c] = h;
      w2l[oc * 128 + c] = f2bf(acc - bflo(h));
    } else if (idx < 8256) {
      int oc = idx - 8192;
      float acc = 0.f;
      for (int m = 0; m < 128; ++m)
        acc += conv_w[oc * 128 + m] * out_b[m];
      b2[oc] = acc + conv_b[oc];
    }
  } else {
    // grid
    int idx = (bb - 3137) * 256 + t;  // 245760
    int n = idx % NTRI;
    int bj = idx / NTRI;
    int plane = n >> 12, rem = n & 4095;
    float fa = (float)(rem & 63), fb = (float)(rem >> 6);
    float cx, cy, cz;
    if (plane == 0)      { cx = fa;    cy = 31.5f; cz = fb; }
    else if (plane == 1) { cx = fa;    cy = fb;    cz = 31.5f; }
    else                 { cx = 31.5f; cy = fa;    cz = fb; }
    const float s2 = 2.20002f;
    cx = (cx / 63.0f - 0.5f) * s2;
    cy = (cy / 63.0f - 0.5f) * s2;
    cz = (cz / 63.0f - 0.5f) * s2;
    const float* P = &proj[bj * 16];
    float d0 = cx * P[0] + cy * P[1] + cz * P[2] + P[3];
    float d1 = cx * P[4] + cy * P[5] + cz * P[6] + P[7];
    float d2 = cx * P[8] + cy * P[9] + cz * P[10] + P[11];
    float x = d0 / d2 / 223.0f;
    float y = d1 / d2 / 223.0f;
    float gx = fminf(fmaxf((x - 0.5f) * 2.0f, -1.0f), 1.0f);
    float gy = fminf(fmaxf((y - 0.5f) * 2.0f, -1.0f), 1.0f);
    float ix = (gx + 1.0f) * 7.5f, iy = (gy + 1.0f) * 7.5f;
    float fx = floorf(ix), fy = floorf(iy);
    float wx = ix - fx, wy = iy - fy;
    int x0 = (int)fx; x0 = x0 < 0 ? 0 : (x0 > 15 ? 15 : x0);
    int y0 = (int)fy; y0 = y0 < 0 ? 0 : (y0 > 15 ? 15 : y0);
    int x1 = x0 + 1 > 15 ? 15 : x0 + 1;
    int y1 = y0 + 1 > 15 ? 15 : y0 + 1;
    int pack = x0 | (x1 << 8) | (y0 << 16) | (y1 << 24);
    gtab[idx] = make_float4(wx, wy, __int_as_float(pack), 0.f);
  }
}

// kvpv MFMA GEMM: C[5120][256] = imgrows(bf16) @ wTc^T + pekv, stored bf16.
// Output column remap: channel-group interleave so k_main loads K4+V4 as one
// uint4: old col c<128 (K ch c) -> (c>>2)*8 + (c&3); c>=128 (V) -> ...+4.
#define LDA 72
__global__ __launch_bounds__(256) void k_kv(const float* __restrict__ img,
    const unsigned short* __restrict__ wTc, const float* __restrict__ pekv,
    unsigned short* __restrict__ kv16) {
  __shared__ unsigned short sA[32 * LDA];
  __shared__ unsigned short sB[64 * LDA];
  int t = threadIdx.x;
  int gm = blockIdx.x >> 2;  // 0..159 (32-row tile)
  int gn = blockIdx.x & 3;   // 0..3
  int r0 = gm * 32, c0 = gn * 64;
  int lane = t & 63, w = t >> 6;
  int wm = w & 1, wn = w >> 1;
  int lrow = lane & 15, quad = lane >> 4;
  int srow = t >> 3, schunk = t & 7;   // staging: 16B chunk per thread
  int bj = gm >> 3;                    // uniform per block (32 | 256)
  f32x4 acc0 = {0,0,0,0}, acc1 = {0,0,0,0};

  float4 pA0, pA1;
  short8 pB0, pB1;
  auto issue = [&](int kt) {
    int k0 = kt * 64;
    const float4* s = (const float4*)&img[(size_t)(r0 + srow + bj + 1) * 1280 + k0 + schunk * 8];
    pA0 = s[0]; pA1 = s[1];
    pB0 = *(const short8*)&wTc[(size_t)(c0 + srow) * 1280 + k0 + schunk * 8];
    pB1 = *(const short8*)&wTc[(size_t)(c0 + srow + 32) * 1280 + k0 + schunk * 8];
  };
  issue(0);

  for (int kt = 0; kt < 20; ++kt) {
    __syncthreads();
    {
      short8 av;
      av[0] = (short)f2bf(pA0.x); av[1] = (short)f2bf(pA0.y);
      av[2] = (short)f2bf(pA0.z); av[3] = (short)f2bf(pA0.w);
      av[4] = (short)f2bf(pA1.x); av[5] = (short)f2bf(pA1.y);
      av[6] = (short)f2bf(pA1.z); av[7] = (short)f2bf(pA1.w);
      *(short8*)&sA[srow * LDA + schunk * 8] = av;
      *(short8*)&sB[srow * LDA + schunk * 8] = pB0;
      *(short8*)&sB[(srow + 32) * LDA + schunk * 8] = pB1;
    }
    __syncthreads();
    if (kt < 19) issue(kt + 1);  // in flight over the MFMA section
#pragma unroll
    for (int kk = 0; kk < 2; ++kk) {
      int kof = kk * 32 + quad * 8;
      short8 a  = *(const short8*)&sA[(wm * 16 + lrow) * LDA + kof];
      short8 b0 = *(const short8*)&sB[(wn * 32 + lrow) * LDA + kof];
      short8 b1 = *(const short8*)&sB[(wn * 32 + 16 + lrow) * LDA + kof];
      acc0 = __builtin_amdgcn_mfma_f32_16x16x32_bf16(a, b0, acc0, 0, 0, 0);
      acc1 = __builtin_amdgcn_mfma_f32_16x16x32_bf16(a, b1, acc1, 0, 0, 0);
    }
  }
  f32x4 accs[2] = {acc0, acc1};
#pragma unroll
  for (int ni = 0; ni < 2; ++ni)
#pragma unroll
    for (int r = 0; r < 4; ++r) {
      int grow = r0 + wm * 16 + quad * 4 + r;
      int gcol = c0 + wn * 32 + ni * 16 + lrow;
      int ncol = (gcol < 128) ? (((gcol >> 2) << 3) | (gcol & 3))
                              : ((((gcol - 128) >> 2) << 3) | 4 | (gcol & 3));
      kv16[(size_t)grow * 256 + ncol] =
          f2bf(accs[ni][r] + pekv[(grow & 255) * 256 + gcol]);
    }
}

// phase-3 j-body: G read from LDS (broadcast: 32 lanes share pt -> same
// addr, conflict-free). Arithmetic identical to rounds 7-12.
#define DO_J(J, VST, SC) {                                                     \
    float4 G = sGT4[J * 32 + pt];                                              \
    int pack = __float_as_int(G.z);                                            \
    int x0 = pack & 255, x1 = (pack >> 8) & 255;                               \
    int y0 = (pack >> 16) & 255, y1 = (pack >> 24) & 255;                      \
    float wx = G.x, wy = G.y;                                                  \
    const unsigned short* r0 = Vb + J * 65536 + y0 * 4096;                     \
    const unsigned short* r1 = Vb + J * 65536 + y1 * 4096;                     \
    int i0 = x0 * 256 + sub * 8, i1 = x1 * 256 + sub * 8;                      \
    uint4 Q00 = *(const uint4*)(r0 + i0), Q01 = *(const uint4*)(r0 + i1);      \
    uint4 Q10 = *(const uint4*)(r1 + i0), Q11 = *(const uint4*)(r1 + i1);      \
    float w00 = (1.f - wx) * (1.f - wy), w01 = wx * (1.f - wy);                \
    float w10 = (1.f - wx) * wy, w11 = wx * wy;                                \
    float4 kc, vc;                                                             \
    kc.x = bflo(Q00.x) * w00 + bflo(Q01.x) * w01 + bflo(Q10.x) * w10 + bflo(Q11.x) * w11; \
    kc.y = bfhi(Q00.x) * w00 + bfhi(Q01.x) * w01 + bfhi(Q10.x) * w10 + bfhi(Q11.x) * w11; \
    kc.z = bflo(Q00.y) * w00 + bflo(Q01.y) * w01 + bflo(Q10.y) * w10 + bflo(Q11.y) * w11; \
    kc.w = bfhi(Q00.y) * w00 + bfhi(Q01.y) * w01 + bfhi(Q10.y) * w10 + bfhi(Q11.y) * w11; \
    vc.x = bflo(Q00.z) * w00 + bflo(Q01.z) * w01 + bflo(Q10.z) * w10 + bflo(Q11.z) * w11; \
    vc.y = bfhi(Q00.z) * w00 + bfhi(Q01.z) * w01 + bfhi(Q10.z) * w10 + bfhi(Q11.z) * w11; \
    vc.z = bflo(Q00.w) * w00 + bflo(Q01.w) * w01 + bflo(Q10.w) * w10 + bflo(Q11.w) * w11; \
    vc.w = bfhi(Q00.w) * w00 + bfhi(Q01.w) * w01 + bfhi(Q10.w) * w10 + bfhi(Q11.w) * w11; \
    VST = vc;                                                                  \
    float pa = qp4.x * kc.x + qp4.y * kc.y + qp4.z * kc.z + qp4.w * kc.w;      \
    pa += __shfl_xor(pa, 1);                                                   \
    pa += __shfl_xor(pa, 2);                                                   \
    SC = pa * 0.25f;                                                           \
  }

// fused: split-bf16 MFMA qp GEMM -> bf16 gather/lerp attention (batch
// softmax, interleaved uint4 K|V, gtab staged through freed sTQ LDS to cut
// ~20 VGPR of prefetch state, __expf) -> split-bf16 MFMA out-proj.
// LDS 25344 B unchanged (sGT overlays dead sTQ).
__global__ __launch_bounds__(256, 2) void k_main(const float* __restrict__ tri,
    const unsigned short* __restrict__ cqwh, const unsigned short* __restrict__ cqwl,
    const float* __restrict__ peq,
    const unsigned short* __restrict__ w2h, const unsigned short* __restrict__ w2l,
    const float* __restrict__ b2,
    const unsigned short* __restrict__ kv16, const float4* __restrict__ gtab,
    float* __restrict__ outp) {
  __shared__ float smem[32 * 132 + 64 * 33];  // 25344 B
  float* sQP = smem;                  // [32][132] qp fp32 (phase 2..3)
  float* sO2 = smem;                  // overlay: O [pt][132] (written in 3)
  float* sTQ = smem + 32 * 132;       // [64][33] tq fp32 (phases 1-2)
  float4* sGT4 = (float4*)(smem + 32 * 132);  // overlay: gtab [j][pt] (ph 3)

  int t = threadIdx.x;
  int lane = t & 63, w = t >> 6;
  int b = blockIdx.x / 384;
  int n0 = (blockIdx.x % 384) * 32;

  // issue this block's gtab slice load NOW (160 float4, coalesced per-j);
  // latency covered by phases 1-2, landed into LDS after phase 2.
  float4 myg;
  {
    int gj = t >> 5, gpt = t & 31;
    if (t < 160)
      myg = gtab[(size_t)(b * 5 + gj) * NTRI + n0 + gpt];
  }

  // phase 1: stage tq fp32 -> LDS [k][pt] pitch 33
  for (int it = 0; it < 8; ++it) {
    int e = it * 256 + t;
    int k = e >> 5, pt = e & 31;
    sTQ[k * 33 + pt] = tri[(size_t)(b * 64 + k) * NTRI + n0 + pt];
  }
  __syncthreads();

  // phase 2: QP[pt][c] = tq @ cqw^T + peq via split-bf16 MFMA (validated r10)
  {
    int wm = w & 1, wn = w >> 1;
    int lrow = lane & 15, quad = lane >> 4;
    short8 ah0, al0, ah1, al1;
#pragma unroll
    for (int j = 0; j < 8; ++j) {
      float v0 = sTQ[(quad * 8 + j) * 33 + wm * 16 + lrow];
      float v1 = sTQ[(32 + quad * 8 + j) * 33 + wm * 16 + lrow];
      unsigned h0 = f2bf(v0);
      ah0[j] = (short)h0; al0[j] = (short)f2bf(v0 - bflo(h0));
      unsigned h1 = f2bf(v1);
      ah1[j] = (short)h1; al1[j] = (short)f2bf(v1 - bflo(h1));
    }
    const short8* Bh = (const short8*)&cqwh[(wn * 64 + lrow) * 64 + quad * 8];
    const short8* Bl = (const short8*)&cqwl[(wn * 64 + lrow) * 64 + quad * 8];
    f32x4 acc0 = {0,0,0,0}, acc1 = {0,0,0,0}, acc2 = {0,0,0,0}, acc3 = {0,0,0,0};
    acc0 = mfma3(ah0, al0, Bh[0],   Bl[0],   acc0);   // nt=0 ks=0
    acc0 = mfma3(ah1, al1, Bh[4],   Bl[4],   acc0);   // nt=0 ks=1
    acc1 = mfma3(ah0, al0, Bh[128], Bl[128], acc1);   // nt=1
    acc1 = mfma3(ah1, al1, Bh[132], Bl[132], acc1);
    acc2 = mfma3(ah0, al0, Bh[256], Bl[256], acc2);   // nt=2
    acc2 = mfma3(ah1, al1, Bh[260], Bl[260], acc2);
    acc3 = mfma3(ah0, al0, Bh[384], Bl[384], acc3);   // nt=3
    acc3 = mfma3(ah1, al1, Bh[388], Bl[388], acc3);
    int pt0 = wm * 16 + quad * 4;
    const float* pq = &peq[(size_t)(n0 + pt0) * 128 + wn * 64 + lrow];
#pragma unroll
    for (int r = 0; r < 4; ++r) {
      float* qrow = &sQP[(pt0 + r) * 132 + wn * 64 + lrow];
      qrow[0]  = acc0[r] + pq[r * 128 + 0];
      qrow[16] = acc1[r] + pq[r * 128 + 16];
      qrow[32] = acc2[r] + pq[r * 128 + 32];
      qrow[48] = acc3[r] + pq[r * 128 + 48];
    }
  }
  __syncthreads();

  // phase 3a: land the gtab slice into the freed sTQ region
  if (t < 160) sGT4[t] = myg;
  __syncthreads();

  // phase 3: attention. 32 lanes per point, 4 channels per lane.
  {
    int sub = lane & 31, half = lane >> 5, c4 = sub * 4;
    int pt0 = w * 2 + half;
    const unsigned short* Vb = kv16 + (size_t)b * 5 * 65536;
    for (int s = 0; s < 4; ++s) {
      int pt = s * 8 + pt0;
      float4 qp4 = *(const float4*)&sQP[pt * 132 + c4];
      float4 v0, v1, v2, v3, v4;
      float s0, s1, s2, s3, s4;
      DO_J(0, v0, s0)
      DO_J(1, v1, s1)
      DO_J(2, v2, s2)
      DO_J(3, v3, s3)
      DO_J(4, v4, s4)
      float mx = fmaxf(fmaxf(fmaxf(s0, s1), fmaxf(s2, s3)), s4);
      float e0 = __expf(s0 - mx), e1 = __expf(s1 - mx), e2 = __expf(s2 - mx);
      float e3 = __expf(s3 - mx), e4 = __expf(s4 - mx);
      float inv = 1.0f / (e0 + e1 + e2 + e3 + e4);
      float4 oa;
      oa.x = (e0 * v0.x + e1 * v1.x + e2 * v2.x + e3 * v3.x + e4 * v4.x) * inv;
      oa.y = (e0 * v0.y + e1 * v1.y + e2 * v2.y + e3 * v3.y + e4 * v4.y) * inv;
      oa.z = (e0 * v0.z + e1 * v1.z + e2 * v2.z + e3 * v3.z + e4 * v4.z) * inv;
      oa.w = (e0 * v0.w + e1 * v1.w + e2 * v2.w + e3 * v3.w + e4 * v4.w) * inv;
      *(float4*)&sO2[pt * 132 + c4] = oa;   // in-place, same pitch: race-free
    }
  }
  __syncthreads();

  // phase 4: FO[oc][pt] = W2 @ O + b2 via split-bf16 MFMA (validated r9).
  {
    int lrow = lane & 15, quad = lane >> 4;
    int oc0 = w * 16;
    const short8* Wh = (const short8*)&w2h[(oc0 + lrow) * 128 + quad * 8];
    const short8* Wl = (const short8*)&w2l[(oc0 + lrow) * 128 + quad * 8];
    f32x4 acc0 = {0,0,0,0}, acc1 = {0,0,0,0};
#pragma unroll
    for (int ks = 0; ks < 4; ++ks) {
      short8 wh = Wh[ks * 4], wl = Wl[ks * 4];
      const float* o0 = &sO2[lrow * 132 + ks * 32 + quad * 8];
      const float* o1 = &sO2[(16 + lrow) * 132 + ks * 32 + quad * 8];
      short8 bh0, bl0, bh1, bl1;
#pragma unroll
      for (int j = 0; j < 8; ++j) {
        float v0 = o0[j];
        unsigned h0 = f2bf(v0);
        bh0[j] = (short)h0; bl0[j] = (short)f2bf(v0 - bflo(h0));
        float v1 = o1[j];
        unsigned h1 = f2bf(v1);
        bh1[j] = (short)h1; bl1[j] = (short)f2bf(v1 - bflo(h1));
      }
      acc0 = mfma3(wh, wl, bh0, bl0, acc0);
      acc1 = mfma3(wh, wl, bh1, bl1, acc1);
    }
    float4 bb4 = *(const float4*)&b2[oc0 + quad * 4];
    size_t obase = (size_t)(b * 64 + oc0 + quad * 4) * NTRI + n0;
#pragma unroll
    for (int r = 0; r < 4; ++r) {
      float brv = (r == 0) ? bb4.x : (r == 1) ? bb4.y : (r == 2) ? bb4.z : bb4.w;
      outp[obase + (size_t)r * NTRI + lrow]      = acc0[r] + brv;
      outp[obase + (size_t)r * NTRI + 16 + lrow] = acc1[r] + brv;
    }
  }
}

extern "C" void kernel_launch(void* const* d_in, const int* in_sizes, int n_in,
                              void* d_out, int out_size, void* d_ws, size_t ws_size,
                              hipStream_t stream) {
  const float* tri    = (const float*)d_in[0];
  const float* img    = (const float*)d_in[1];
  const float* proj   = (const float*)d_in[2];
  const float* k_w    = (const float*)d_in[4];
  const float* k_b    = (const float*)d_in[5];
  const float* q_w    = (const float*)d_in[6];
  const float* q_b    = (const float*)d_in[7];
  const float* v_w    = (const float*)d_in[8];
  const float* v_b    = (const float*)d_in[9];
  const float* in_w   = (const float*)d_in[10];
  const float* in_b   = (const float*)d_in[11];
  const float* out_w  = (const float*)d_in[12];
  const float* out_b  = (const float*)d_in[13];
  const float* conv_w = (const float*)d_in[14];
  const float* conv_b = (const float*)d_in[15];
  float* ws = (float*)d_ws;
  unsigned short* wTc  = (unsigned short*)(ws + OFF_WT);
  float* pekv = ws + OFF_PEKV;
  unsigned short* cqwh = (unsigned short*)(ws + OFF_CQWT);
  unsigned short* cqwl = cqwh + 8192;
  float* peq  = ws + OFF_PEQ;
  unsigned short* w2h = (unsigned short*)(ws + OFF_W2T);
  unsigned short* w2l = w2h + 8192;
  float* b2   = ws + OFF_B2;
  float* inwT = ws + OFF_INWT;
  unsigned short* kv16 = (unsigned short*)(ws + OFF_KVPV);
  float* gtab = ws + OFF_GTAB;
  float* outp = (float*)d_out;

  k_inwT<<<192, 256, 0, stream>>>(in_w, inwT);
  k_pre<<<4097, 256, 0, stream>>>(inwT, k_w, v_w, k_b, v_b, in_b, q_w, q_b,
                                  conv_w, out_w, out_b, conv_b, proj,
                                  wTc, pekv, cqwh, cqwl, peq, w2h, w2l, b2,
                                  (float4*)gtab);
  k_kv<<<640, 256, 0, stream>>>(img, wTc, pekv, kv16);
  k_main<<<1536, 256, 0, stream>>>(tri, cqwh, cqwl, peq, w2h, w2l, b2, kv16,
                                   (const float4*)gtab, outp);
}